// Round 2
// baseline (152.977 us; speedup 1.0000x reference)
//
#include <hip/hip_runtime.h>

// norm_conv: im2col(3x3 reflect) -> row-normalize -> GEMM[576x64], fused.
// R2: occupancy attack. Round-1 held B-frags in 144 regs -> 250 unified regs
// -> 2 waves/SIMD cap. Now: ks-outer loop, B streamed from L2 (72 KiB table,
// distance-1 prefetch), acc for 2mt x 4nt = 32 regs live. 1024 blocks
// (8-out-row quarters) x 512 thr, LDS 46 KB -> 2-3 blocks/CU, 16+ waves/CU.
//   out = (patches@W - mean*colsum(W)) * inv_std   (norm folded into epilogue)

#define STRIDE 68            // ushorts per pixel in LDS (136 B = 34 banks)
#define NROW   10
#define NPIX   320           // 10 rows x 32 cols

typedef __attribute__((ext_vector_type(8))) short bf16x8;
typedef __attribute__((ext_vector_type(4))) short bf16x4;
typedef __attribute__((ext_vector_type(4))) float f32x4;

__device__ __forceinline__ unsigned short f2bf(float f) {
    union { float f; unsigned u; } v; v.f = f;
    unsigned r = v.u + 0x7FFFu + ((v.u >> 16) & 1u);   // RNE
    return (unsigned short)(r >> 16);
}

__device__ __forceinline__ int reflect32(int x) {      // jnp.pad 'reflect', pad=1
    x = (x < 0) ? -x : x;
    return (x > 31) ? (62 - x) : x;
}

// blocks 0..17: pack W (fp32->bf16) into per-lane B-frag layout wf[4][18][64].
// block 18: scol[o] = sum_k bf16(W[k][o]) (matches the bf16 GEMM's effective W).
// B[k'][o]: o = ntg*16 + (lane&15), k' = ks*32 + (lane>>4)*8 + j,
// reordered k' = (kh*3+kw)*64 + c  <->  reference k = c*9 + (kh*3+kw).
__global__ void prep_kernel(const float* __restrict__ W, uint4* __restrict__ wf,
                            float* __restrict__ scolg) {
    if (blockIdx.x == 18) {
        __shared__ float red[256];
        int t = threadIdx.x;
        int o = t & 63, kq = t >> 6;
        float s = 0.f;
        for (int k = kq * 144; k < kq * 144 + 144; ++k) {
            union { unsigned u; float f; } cv;
            cv.u = ((unsigned)f2bf(W[k * 64 + o])) << 16;
            s += cv.f;
        }
        red[t] = s;
        __syncthreads();
        if (t < 64) scolg[t] = red[t] + red[t + 64] + red[t + 128] + red[t + 192];
        return;
    }
    int idx = blockIdx.x * 256 + threadIdx.x;   // 0..4607
    int lane = idx & 63;
    int ks   = (idx >> 6) % 18;
    int ntg  = idx / 1152;
    int quad = lane >> 4;
    int o    = ntg * 16 + (lane & 15);
    unsigned short v[8];
    #pragma unroll
    for (int j = 0; j < 8; ++j) {
        int kp = ks * 32 + quad * 8 + j;
        int c  = kp & 63;
        int s  = kp >> 6;
        v[j] = f2bf(W[(c * 9 + s) * 64 + o]);
    }
    uint4 r;
    r.x = (unsigned)v[0] | ((unsigned)v[1] << 16);
    r.y = (unsigned)v[2] | ((unsigned)v[3] << 16);
    r.z = (unsigned)v[4] | ((unsigned)v[5] << 16);
    r.w = (unsigned)v[6] | ((unsigned)v[7] << 16);
    wf[idx] = r;
}

__global__ __launch_bounds__(512, 4)
void norm_conv_kernel(const float* __restrict__ a,
                      const uint4* __restrict__ wf,
                      const float* __restrict__ scolg,
                      float* __restrict__ out) {
    __shared__ unsigned short img[NPIX * STRIDE];   // 43,520 B
    __shared__ float sums[2 * NPIX];                // csum|cssq; later (mean,inv)[256] pairs

    const int tid = threadIdx.x;
    const int b   = blockIdx.x >> 2;
    const int q   = blockIdx.x & 3;                 // quarter: out rows [8q, 8q+8)
    const int row_base = (q == 0) ? 0 : (q == 3 ? 22 : 8 * q - 1);  // staged rows [rb, rb+10)
    const int lane = tid & 63;
    const int wid  = tid >> 6;                      // 8 waves; wave = out row q*8+wid
    const int quad = lane >> 4;
    const int mlan = lane & 15;

    // ---- stage 10 rows x 32 cols x 64ch: fp32 -> bf16 LDS + fp32 channel sums ----
    // unit u = (pixel p, channel-half ch): 640 units over 512 threads.
    const float* Ab = a + (size_t)b * 65536 + row_base * 32;
    for (int u = tid; u < 640; u += 512) {
        int p  = u >> 1;
        int ch = (u & 1) * 32;
        float s = 0.f, qq = 0.f;
        unsigned short* row = &img[p * STRIDE + ch];
        #pragma unroll
        for (int c4 = 0; c4 < 32; c4 += 4) {
            float v0 = Ab[(ch + c4) * 1024 + p];     // coalesced: p consecutive per lane-pair
            float v1 = Ab[(ch + c4 + 1) * 1024 + p];
            float v2 = Ab[(ch + c4 + 2) * 1024 + p];
            float v3 = Ab[(ch + c4 + 3) * 1024 + p];
            s  += (v0 + v1) + (v2 + v3);
            qq += (v0 * v0 + v1 * v1) + (v2 * v2 + v3 * v3);
            uint2 pk;
            pk.x = (unsigned)f2bf(v0) | ((unsigned)f2bf(v1) << 16);
            pk.y = (unsigned)f2bf(v2) | ((unsigned)f2bf(v3) << 16);
            *(uint2*)&row[c4] = pk;                  // ds_write_b64, conflict-free
        }
        // combine the two channel-halves (adjacent lanes)
        s  += __shfl_xor(s, 1, 64);
        qq += __shfl_xor(qq, 1, 64);
        if ((u & 1) == 0) { sums[p] = s; sums[NPIX + p] = qq; }
    }
    __syncthreads();

    // ---- per-output-pixel mean / inv-std via 3x3 box of channel sums ----
    float mean = 0.f, inv = 0.f;
    if (tid < 256) {
        int hg = q * 8 + (tid >> 5);
        int wg = tid & 31;
        float s = 0.f, ss = 0.f;
        #pragma unroll
        for (int kh = 0; kh < 3; ++kh) {
            int hr = reflect32(hg + kh - 1) - row_base;
            #pragma unroll
            for (int kw = 0; kw < 3; ++kw) {
                int p = hr * 32 + reflect32(wg + kw - 1);
                s  += sums[p];
                ss += sums[NPIX + p];
            }
        }
        mean = s * (1.0f / 576.0f);
        inv  = rsqrtf((ss - s * mean) * (1.0f / 575.0f));   // ddof=1
    }
    __syncthreads();
    if (tid < 256) { sums[tid * 2] = mean; sums[tid * 2 + 1] = inv; }
    __syncthreads();

    // ---- per-lane colsum(W) for the 4 n-tiles (L2-hot) ----
    float So[4];
    #pragma unroll
    for (int nt = 0; nt < 4; ++nt) So[nt] = scolg[nt * 16 + mlan];

    // ---- packed A addressing: off(mt,ks) = rowb[kh] + colb[mt&1][kw] + (ks&1)*64 ----
    int rowb[3], colb[2][3];
    #pragma unroll
    for (int kh = 0; kh < 3; ++kh)
        rowb[kh] = (reflect32(q * 8 + wid + kh - 1) - row_base) * (32 * STRIDE * 2) + quad * 16;
    #pragma unroll
    for (int j = 0; j < 2; ++j)
        #pragma unroll
        for (int kw = 0; kw < 3; ++kw)
            colb[j][kw] = reflect32(j * 16 + mlan + kw - 1) * (STRIDE * 2);

    // ---- main loop: ks outer (18), B prefetched from L2, 2 mt x 4 nt acc ----
    f32x4 acc[2][4];
    #pragma unroll
    for (int mt = 0; mt < 2; ++mt)
        #pragma unroll
        for (int nt = 0; nt < 4; ++nt)
            acc[mt][nt] = (f32x4){0.f, 0.f, 0.f, 0.f};

    const uint4* bp = wf + lane;
    uint4 bnx[4];
    #pragma unroll
    for (int nt = 0; nt < 4; ++nt) bnx[nt] = bp[nt * 18 * 64];

    const char* imgc = (const char*)img;
    #pragma unroll
    for (int ks = 0; ks < 18; ++ks) {
        uint4 bc[4];
        #pragma unroll
        for (int nt = 0; nt < 4; ++nt) bc[nt] = bnx[nt];
        if (ks < 17) {
            #pragma unroll
            for (int nt = 0; nt < 4; ++nt) bnx[nt] = bp[(nt * 18 + ks + 1) * 64];
        }
        const int khi = (ks >> 1) / 3;
        const int kwi = (ks >> 1) % 3;
        const int coff = (ks & 1) * 64;
        #pragma unroll
        for (int mt = 0; mt < 2; ++mt) {
            int off = rowb[khi] + colb[mt][kwi] + coff;
            bf16x4 flo = *(const bf16x4*)(imgc + off);       // ds_read_b64 x2
            bf16x4 fhi = *(const bf16x4*)(imgc + off + 8);
            bf16x8 af  = __builtin_shufflevector(flo, fhi, 0, 1, 2, 3, 4, 5, 6, 7);
            #pragma unroll
            for (int nt = 0; nt < 4; ++nt) {
                union { uint4 u; bf16x8 v; } cb; cb.u = bc[nt];
                acc[mt][nt] = __builtin_amdgcn_mfma_f32_16x16x32_bf16(af, cb.v, acc[mt][nt], 0, 0, 0);
            }
        }
    }

    // ---- epilogue: D row=quad*4+r (pixel), col=lane&15 (channel within nt) ----
    float* outB = out + (size_t)b * 65536 + q * 256;
    #pragma unroll
    for (int mt = 0; mt < 2; ++mt) {
        int l0 = (wid * 2 + mt) * 16 + quad * 4;
        float mn[4], iv[4];
        #pragma unroll
        for (int r = 0; r < 4; ++r) {
            mn[r] = sums[(l0 + r) * 2];              // broadcast reads (free)
            iv[r] = sums[(l0 + r) * 2 + 1];
        }
        #pragma unroll
        for (int nt = 0; nt < 4; ++nt) {
            f32x4 rr;
            #pragma unroll
            for (int r = 0; r < 4; ++r)
                rr[r] = (acc[mt][nt][r] - mn[r] * So[nt]) * iv[r];
            *(f32x4*)(outB + (nt * 16 + mlan) * 1024 + l0) = rr;   // 64B/line per (o,mt) per inst
        }
    }
}

extern "C" void kernel_launch(void* const* d_in, const int* in_sizes, int n_in,
                              void* d_out, int out_size, void* d_ws, size_t ws_size,
                              hipStream_t stream) {
    const float* a = (const float*)d_in[0];
    const float* w = (const float*)d_in[1];
    float* out = (float*)d_out;
    uint4* wf = (uint4*)d_ws;                                  // 73,728 B
    float* scolg = (float*)((char*)d_ws + 73728);              // 256 B
    prep_kernel<<<dim3(19), dim3(256), 0, stream>>>(w, wf, scolg);
    norm_conv_kernel<<<dim3(1024), dim3(512), 0, stream>>>(a, wf, scolg, out);
}